// Round 6
// baseline (170.818 us; speedup 1.0000x reference)
//
#include <hip/hip_runtime.h>

#define BB 8
#define NN 4096
#define DD 128
#define KK 1024
#define KSPLIT 4
#define KCOLS 256                 // cols per split
#define KSTEP 32
#define NSTEPS (KCOLS / KSTEP)    // 8

typedef _Float16 f16;
typedef f16 f16x8 __attribute__((ext_vector_type(8)));
typedef f16 f16x4 __attribute__((ext_vector_type(4)));
typedef float f32x16 __attribute__((ext_vector_type(16)));

#define MFMA32x16 __builtin_amdgcn_mfma_f32_32x32x16_f16

// ---- ws layout ----
// [0,32KB)       e2    f32 [8][1024]
// OFF_HI +2MB    eThi  f16 [8][1024][128]
// OFF_LO +2MB    eTlo  f16 [8][1024][128]
// OFF_TF +4MB    eTf   f32 [8][1024][128]  (exact, gather source)
// OFF_CAND +1MB  cand  float2 [8][4096][KSPLIT] (minv, k-as-float-bits)
#define OFF_HI 32768
#define OFF_LO (OFF_HI + 2097152)
#define OFF_TF (OFF_LO + 2097152)
#define OFF_CAND (OFF_TF + 4194304)
#define LOSS_IDX ((size_t)BB * NN * DD)

__device__ __forceinline__ void gload16(const void* g, void* l) {
  __builtin_amdgcn_global_load_lds(
      (const __attribute__((address_space(1))) void*)g,
      (__attribute__((address_space(3))) void*)l, 16, 0, 0);
}

// ============= prep: transpose + f16 hi/lo split + |e|^2 + loss-zero ========
__launch_bounds__(256)
__global__ void vq_prep(const float* __restrict__ emb, char* __restrict__ ws,
                        float* __restrict__ out) {
  __shared__ float tile[32][129];
  const int t  = threadIdx.x;
  const int k0 = blockIdx.x * 32;
  const int b  = blockIdx.y;
  float* e2  = (float*)ws;
  f16*   ehi = (f16*)(ws + OFF_HI);
  f16*   elo = (f16*)(ws + OFF_LO);
  float* etf = (float*)(ws + OFF_TF);

  if (blockIdx.x == 0 && blockIdx.y == 0 && t == 0) out[LOSS_IDX] = 0.f;

  const float* eb = emb + (size_t)b * DD * KK;
#pragma unroll
  for (int it = 0; it < 16; ++it) {
    int idx = it * 256 + t;
    int d = idx >> 5, k = idx & 31;
    tile[k][d] = eb[(size_t)d * KK + k0 + k];
  }
  __syncthreads();
#pragma unroll
  for (int rep = 0; rep < 4; ++rep) {
    int idx = rep * 256 + t;
    int k = idx >> 5, seg = idx & 31;
    float4 v = *(const float4*)&tile[k][seg * 4];
    size_t base = (size_t)(b * KK + k0 + k) * DD + seg * 4;
    *(float4*)(etf + base) = v;
    f16 h0 = (f16)v.x, h1 = (f16)v.y, h2 = (f16)v.z, h3 = (f16)v.w;
    f16x4 hv = {h0, h1, h2, h3};
    f16x4 lv = {(f16)(v.x - (float)h0), (f16)(v.y - (float)h1),
                (f16)(v.z - (float)h2), (f16)(v.w - (float)h3)};
    *(f16x4*)(ehi + base) = hv;
    *(f16x4*)(elo + base) = lv;
  }
  if (t < 32) {
    double acc = 0.0;
#pragma unroll 16
    for (int d = 0; d < DD; ++d) { float v = tile[t][d]; acc += (double)v * (double)v; }
    e2[b * KK + k0 + t] = (float)acc;
  }
}

// ========= p1: f16x3 MFMA partial distances + per-split argmin =============
__launch_bounds__(256, 4)
__global__ void vq_p1(const float* __restrict__ x, const char* __restrict__ ws,
                      float2* __restrict__ cand) {
  __shared__ __align__(16) char smem[32768];   // 2 x (hi 8KB | lo 8KB)
  const float* e2g = (const float*)ws;
  const f16*   ehi = (const f16*)(ws + OFF_HI);
  const f16*   elo = (const f16*)(ws + OFF_LO);

  const int t = threadIdx.x;
  const int w = t >> 6, lane = t & 63;
  const int r = lane & 31, hb = lane >> 5;
  const int b = blockIdx.y, n0 = blockIdx.x * 128;
  const int sp = blockIdx.z, kb0 = sp * KCOLS;

  // A: 32 rows/wave, f16 hi/lo split in regs (k-slot = hb*8 + j)
  f16x8 ahi[8], alo[8];
  {
    const float* xrow = x + (size_t)(b * NN + n0 + w * 32 + r) * DD;
#pragma unroll
    for (int dc = 0; dc < 8; ++dc) {
      int d0 = dc * 16 + hb * 8;
      float4 f0 = *(const float4*)(xrow + d0);
      float4 f1 = *(const float4*)(xrow + d0 + 4);
      float fv[8] = {f0.x, f0.y, f0.z, f0.w, f1.x, f1.y, f1.z, f1.w};
#pragma unroll
      for (int j = 0; j < 8; ++j) {
        f16 h = (f16)fv[j];
        ahi[dc][j] = h;
        alo[dc][j] = (f16)(fv[j] - (float)h);
      }
    }
  }

  // stage 32 k-rows (hi+lo = 16KB), pre-swizzled source (involution (row&15)<<4)
  auto STAGE = [&](int buf, int ks) {
    const int k0 = kb0 + ks * KSTEP;
    char* hbase = smem + buf * 16384;
    char* lbase = hbase + 8192;
#pragma unroll
    for (int i = 0; i < 2; ++i) {
      int c    = i * 4 + w;                    // 1KB chunk 0..7
      int rloc = c * 4 + (lane >> 4);          // LDS row for this lane's 16B
      int src  = ((lane & 15) << 4) ^ ((rloc & 15) << 4);
      size_t rowb = (size_t)(b * KK + k0 + rloc) << 8;   // 256B rows
      gload16((const char*)ehi + rowb + src, hbase + c * 1024);
      gload16((const char*)elo + rowb + src, lbase + c * 1024);
    }
  };

  float minv[16]; int mink[16];
#pragma unroll
  for (int j = 0; j < 16; ++j) { minv[j] = 3.4e38f; mink[j] = 0; }

  STAGE(0, 0);
  __syncthreads();

  for (int ks = 0; ks < NSTEPS; ++ks) {
    const int cur = ks & 1;
    if (ks < NSTEPS - 1) STAGE(cur ^ 1, ks + 1);
    const char* hbase = smem + cur * 16384;
    const char* lbase = hbase + 8192;
    f32x16 accA = {}, accB = {};
    const int swz = (r & 15) << 4;
#pragma unroll
    for (int dc = 0; dc < 8; ++dc) {
      const int off = (dc * 32 + hb * 16) ^ swz;   // B k-slot: hb*8 + j
      f16x8 bh = *(const f16x8*)(hbase + r * 256 + off);
      f16x8 bl = *(const f16x8*)(lbase + r * 256 + off);
      accA = MFMA32x16(ahi[dc], bh, accA, 0, 0, 0);
      accA = MFMA32x16(alo[dc], bh, accA, 0, 0, 0);
      accB = MFMA32x16(ahi[dc], bl, accB, 0, 0, 0);
    }
    const int   kg  = kb0 + ks * KSTEP + r;
    const float e2v = e2g[b * KK + kg];
#pragma unroll
    for (int j = 0; j < 16; ++j) {
      float s = __builtin_fmaf(-2.f, accA[j] + accB[j], e2v);
      if (s < minv[j]) { minv[j] = s; mink[j] = kg; }   // strict <: first index
    }
    __syncthreads();
  }

  // argmin across the 32 col-lanes (off<32 keeps hb halves separate)
#pragma unroll
  for (int off = 1; off < 32; off <<= 1) {
#pragma unroll
    for (int j = 0; j < 16; ++j) {
      float v2 = __shfl_xor(minv[j], off);
      int   k2 = __shfl_xor(mink[j], off);
      if (v2 < minv[j] || (v2 == minv[j] && k2 < mink[j])) { minv[j] = v2; mink[j] = k2; }
    }
  }
  if (r == 0) {
#pragma unroll
    for (int j = 0; j < 16; ++j) {
      int row = (j & 3) + 8 * (j >> 2) + 4 * hb;   // C/D row map (verified R5 pass)
      int n = n0 + w * 32 + row;
      cand[(size_t)(b * NN + n) * KSPLIT + sp] =
          make_float2(minv[j], __int_as_float(mink[j]));
    }
  }
}

// ========= p2: merge splits + gather + store + loss ========================
__launch_bounds__(256)
__global__ void vq_p2(const float* __restrict__ x, const char* __restrict__ ws,
                      const float2* __restrict__ cand, float* __restrict__ out) {
  __shared__ int   kidx[32];
  __shared__ float wsum[4];
  const float* etf = (const float*)(ws + OFF_TF);
  const int t = threadIdx.x;
  const int row0 = blockIdx.x * 32;     // global row in [0, BB*NN)

  if ((t & 7) == 0) {                   // one thread per row: merge 4 candidates
    int rr = t >> 3;
    const float2* c = cand + (size_t)(row0 + rr) * KSPLIT;
    float bv = c[0].x; int bk = __float_as_int(c[0].y);
#pragma unroll
    for (int s = 1; s < KSPLIT; ++s) {
      float2 p = c[s];
      if (p.x < bv) { bv = p.x; bk = __float_as_int(p.y); }  // splits k-ascending
    }
    kidx[rr] = bk;
  }
  __syncthreads();

  const int rr = t >> 3, part = t & 7;
  const int grow = row0 + rr;
  const int b = grow >> 12;             // NN = 4096
  const int k = kidx[rr];
  const float4* et = (const float4*)(etf + (size_t)(b * KK + k) * DD + part * 16);
  const float4* xr = (const float4*)(x + (size_t)grow * DD + part * 16);
  float4*       ov = (float4*)(out + (size_t)grow * DD + part * 16);
  float lsum = 0.f;
#pragma unroll
  for (int i = 0; i < 4; ++i) {
    float4 q = et[i], xv = xr[i];
    ov[i] = q;
    float d0 = q.x - xv.x, d1 = q.y - xv.y, d2 = q.z - xv.z, d3 = q.w - xv.w;
    lsum += d0 * d0 + d1 * d1 + d2 * d2 + d3 * d3;
  }
#pragma unroll
  for (int off = 1; off < 64; off <<= 1) lsum += __shfl_xor(lsum, off);
  if ((t & 63) == 0) wsum[t >> 6] = lsum;
  __syncthreads();
  if (t == 0)
    atomicAdd(out + LOSS_IDX, (wsum[0] + wsum[1] + wsum[2] + wsum[3]) *
                                  (1.25f / (float)LOSS_IDX));
}

extern "C" void kernel_launch(void* const* d_in, const int* in_sizes, int n_in,
                              void* d_out, int out_size, void* d_ws, size_t ws_size,
                              hipStream_t stream) {
  const float* x   = (const float*)d_in[0];
  const float* emb = (const float*)d_in[1];
  float* out = (float*)d_out;
  char*  ws  = (char*)d_ws;
  float2* cand = (float2*)(ws + OFF_CAND);

  vq_prep<<<dim3(KK / 32, BB), 256, 0, stream>>>(emb, ws, out);
  vq_p1<<<dim3(NN / 128, BB, KSPLIT), 256, 0, stream>>>(x, ws, cand);
  vq_p2<<<dim3((BB * NN) / 32), 256, 0, stream>>>(x, ws, cand, out);
}

// Round 7
// 133.489 us; speedup vs baseline: 1.2796x; 1.2796x over previous
//
#include <hip/hip_runtime.h>

#define BB 8
#define NN 4096
#define DD 128
#define KK 1024
#define KSPLIT 4
#define KCOLS 256                 // cols per split
#define KSTEP 32
#define NSTEPS (KCOLS / KSTEP)    // 8

typedef _Float16 f16;
typedef f16 f16x8 __attribute__((ext_vector_type(8)));
typedef f16 f16x4 __attribute__((ext_vector_type(4)));
typedef float f32x16 __attribute__((ext_vector_type(16)));

#define MFMA32x16 __builtin_amdgcn_mfma_f32_32x32x16_f16

// ---- ws layout ----
// [0,32KB)       e2    f32 [8][1024]
// OFF_HI +2MB    eThi  f16 [8][1024][128]
// OFF_LO +2MB    eTlo  f16 [8][1024][128]
// OFF_TF +4MB    eTf   f32 [8][1024][128]  (exact, gather source)
// OFF_CAND +1MB  cand  float2 [8][4096][KSPLIT] (minv, k-as-float-bits)
#define OFF_HI 32768
#define OFF_LO (OFF_HI + 2097152)
#define OFF_TF (OFF_LO + 2097152)
#define OFF_CAND (OFF_TF + 4194304)
#define LOSS_IDX ((size_t)BB * NN * DD)

__device__ __forceinline__ void gload16(const void* g, void* l) {
  __builtin_amdgcn_global_load_lds(
      (const __attribute__((address_space(1))) void*)g,
      (__attribute__((address_space(3))) void*)l, 16, 0, 0);
}

// ============= prep: transpose + f16 hi/lo split + |e|^2 + loss-zero ========
__launch_bounds__(256)
__global__ void vq_prep(const float* __restrict__ emb, char* __restrict__ ws,
                        float* __restrict__ out) {
  __shared__ float tile[32][129];
  const int t  = threadIdx.x;
  const int k0 = blockIdx.x * 32;
  const int b  = blockIdx.y;
  float* e2  = (float*)ws;
  f16*   ehi = (f16*)(ws + OFF_HI);
  f16*   elo = (f16*)(ws + OFF_LO);
  float* etf = (float*)(ws + OFF_TF);

  if (blockIdx.x == 0 && blockIdx.y == 0 && t == 0) out[LOSS_IDX] = 0.f;

  const float* eb = emb + (size_t)b * DD * KK;
#pragma unroll
  for (int it = 0; it < 16; ++it) {
    int idx = it * 256 + t;
    int d = idx >> 5, k = idx & 31;
    tile[k][d] = eb[(size_t)d * KK + k0 + k];
  }
  __syncthreads();
#pragma unroll
  for (int rep = 0; rep < 4; ++rep) {
    int idx = rep * 256 + t;
    int k = idx >> 5, seg = idx & 31;
    float4 v = *(const float4*)&tile[k][seg * 4];
    size_t base = (size_t)(b * KK + k0 + k) * DD + seg * 4;
    *(float4*)(etf + base) = v;
    f16 h0 = (f16)v.x, h1 = (f16)v.y, h2 = (f16)v.z, h3 = (f16)v.w;
    f16x4 hv = {h0, h1, h2, h3};
    f16x4 lv = {(f16)(v.x - (float)h0), (f16)(v.y - (float)h1),
                (f16)(v.z - (float)h2), (f16)(v.w - (float)h3)};
    *(f16x4*)(ehi + base) = hv;
    *(f16x4*)(elo + base) = lv;
  }
  if (t < 32) {
    double acc = 0.0;
#pragma unroll 16
    for (int d = 0; d < DD; ++d) { float v = tile[t][d]; acc += (double)v * (double)v; }
    e2[b * KK + k0 + t] = (float)acc;
  }
}

// ========= p1: f16x3 MFMA partial distances + per-split argmin =============
__launch_bounds__(256, 2)
__global__ void vq_p1(const float* __restrict__ x, const char* __restrict__ ws,
                      float2* __restrict__ cand) {
  __shared__ __align__(16) char smem[32768];   // 2 x (hi 8KB | lo 8KB)
  const float* e2g = (const float*)ws;
  const f16*   ehi = (const f16*)(ws + OFF_HI);
  const f16*   elo = (const f16*)(ws + OFF_LO);

  const int t = threadIdx.x;
  const int w = t >> 6, lane = t & 63;
  const int r = lane & 31, hb = lane >> 5;
  const int b = blockIdx.y, n0 = blockIdx.x * 128;
  const int sp = blockIdx.z, kb0 = sp * KCOLS;

  // A: 32 rows/wave, f16 hi/lo split in regs (k-slot = hb*8 + j)
  f16x8 ahi[8], alo[8];
  {
    const float* xrow = x + (size_t)(b * NN + n0 + w * 32 + r) * DD;
#pragma unroll
    for (int dc = 0; dc < 8; ++dc) {
      int d0 = dc * 16 + hb * 8;
      float4 f0 = *(const float4*)(xrow + d0);
      float4 f1 = *(const float4*)(xrow + d0 + 4);
      float fv[8] = {f0.x, f0.y, f0.z, f0.w, f1.x, f1.y, f1.z, f1.w};
#pragma unroll
      for (int j = 0; j < 8; ++j) {
        f16 h = (f16)fv[j];
        ahi[dc][j] = h;
        alo[dc][j] = (f16)(fv[j] - (float)h);
      }
    }
  }

  // stage 32 k-rows (hi+lo = 16KB), pre-swizzled source (involution (row&15)<<4)
  auto STAGE = [&](int buf, int ks) {
    const int k0 = kb0 + ks * KSTEP;
    char* hbase = smem + buf * 16384;
    char* lbase = hbase + 8192;
#pragma unroll
    for (int i = 0; i < 2; ++i) {
      int c    = i * 4 + w;                    // 1KB chunk 0..7
      int rloc = c * 4 + (lane >> 4);          // LDS row for this lane's 16B
      int src  = ((lane & 15) << 4) ^ ((rloc & 15) << 4);
      size_t rowb = (size_t)(b * KK + k0 + rloc) << 8;   // 256B rows
      gload16((const char*)ehi + rowb + src, hbase + c * 1024);
      gload16((const char*)elo + rowb + src, lbase + c * 1024);
    }
  };

  float minv[16]; int mink[16];
#pragma unroll
  for (int j = 0; j < 16; ++j) { minv[j] = 3.4e38f; mink[j] = 0; }

  STAGE(0, 0);
  __syncthreads();

  for (int ks = 0; ks < NSTEPS; ++ks) {
    const int cur = ks & 1;
    if (ks < NSTEPS - 1) STAGE(cur ^ 1, ks + 1);
    const char* hbase = smem + cur * 16384;
    const char* lbase = hbase + 8192;
    f32x16 acc = {};                      // single C: xhi*ehi + xlo*ehi + xhi*elo
    const int swz = (r & 15) << 4;
#pragma unroll
    for (int dc = 0; dc < 8; ++dc) {
      const int off = (dc * 32 + hb * 16) ^ swz;   // B k-slot: hb*8 + j
      f16x8 bh = *(const f16x8*)(hbase + r * 256 + off);
      f16x8 bl = *(const f16x8*)(lbase + r * 256 + off);
      acc = MFMA32x16(ahi[dc], bh, acc, 0, 0, 0);
      acc = MFMA32x16(alo[dc], bh, acc, 0, 0, 0);
      acc = MFMA32x16(ahi[dc], bl, acc, 0, 0, 0);
    }
    const int   kg  = kb0 + ks * KSTEP + r;
    const float e2v = e2g[b * KK + kg];
#pragma unroll
    for (int j = 0; j < 16; ++j) {
      float s = __builtin_fmaf(-2.f, acc[j], e2v);
      if (s < minv[j]) { minv[j] = s; mink[j] = kg; }   // strict <: first index
    }
    __syncthreads();
  }

  // argmin across the 32 col-lanes (off<32 keeps hb halves separate)
#pragma unroll
  for (int off = 1; off < 32; off <<= 1) {
#pragma unroll
    for (int j = 0; j < 16; ++j) {
      float v2 = __shfl_xor(minv[j], off);
      int   k2 = __shfl_xor(mink[j], off);
      if (v2 < minv[j] || (v2 == minv[j] && k2 < mink[j])) { minv[j] = v2; mink[j] = k2; }
    }
  }
  if (r == 0) {
#pragma unroll
    for (int j = 0; j < 16; ++j) {
      int row = (j & 3) + 8 * (j >> 2) + 4 * hb;   // C/D row map (verified R5 pass)
      int n = n0 + w * 32 + row;
      cand[(size_t)(b * NN + n) * KSPLIT + sp] =
          make_float2(minv[j], __int_as_float(mink[j]));
    }
  }
}

// ========= p2: merge splits + gather + store + loss ========================
__launch_bounds__(256)
__global__ void vq_p2(const float* __restrict__ x, const char* __restrict__ ws,
                      const float2* __restrict__ cand, float* __restrict__ out) {
  __shared__ int   kidx[32];
  __shared__ float wsum[4];
  const float* etf = (const float*)(ws + OFF_TF);
  const int t = threadIdx.x;
  const int row0 = blockIdx.x * 32;     // global row in [0, BB*NN)

  if ((t & 7) == 0) {                   // one thread per row: merge 4 candidates
    int rr = t >> 3;
    const float2* c = cand + (size_t)(row0 + rr) * KSPLIT;
    float bv = c[0].x; int bk = __float_as_int(c[0].y);
#pragma unroll
    for (int s = 1; s < KSPLIT; ++s) {
      float2 p = c[s];
      if (p.x < bv) { bv = p.x; bk = __float_as_int(p.y); }  // splits k-ascending
    }
    kidx[rr] = bk;
  }
  __syncthreads();

  const int rr = t >> 3, part = t & 7;
  const int grow = row0 + rr;
  const int b = grow >> 12;             // NN = 4096
  const int k = kidx[rr];
  const float4* et = (const float4*)(etf + (size_t)(b * KK + k) * DD + part * 16);
  const float4* xr = (const float4*)(x + (size_t)grow * DD + part * 16);
  float4*       ov = (float4*)(out + (size_t)grow * DD + part * 16);
  float lsum = 0.f;
#pragma unroll
  for (int i = 0; i < 4; ++i) {
    float4 q = et[i], xv = xr[i];
    ov[i] = q;
    float d0 = q.x - xv.x, d1 = q.y - xv.y, d2 = q.z - xv.z, d3 = q.w - xv.w;
    lsum += d0 * d0 + d1 * d1 + d2 * d2 + d3 * d3;
  }
#pragma unroll
  for (int off = 1; off < 64; off <<= 1) lsum += __shfl_xor(lsum, off);
  if ((t & 63) == 0) wsum[t >> 6] = lsum;
  __syncthreads();
  if (t == 0)
    atomicAdd(out + LOSS_IDX, (wsum[0] + wsum[1] + wsum[2] + wsum[3]) *
                                  (1.25f / (float)LOSS_IDX));
}

extern "C" void kernel_launch(void* const* d_in, const int* in_sizes, int n_in,
                              void* d_out, int out_size, void* d_ws, size_t ws_size,
                              hipStream_t stream) {
  const float* x   = (const float*)d_in[0];
  const float* emb = (const float*)d_in[1];
  float* out = (float*)d_out;
  char*  ws  = (char*)d_ws;
  float2* cand = (float2*)(ws + OFF_CAND);

  vq_prep<<<dim3(KK / 32, BB), 256, 0, stream>>>(emb, ws, out);
  vq_p1<<<dim3(NN / 128, BB, KSPLIT), 256, 0, stream>>>(x, ws, cand);
  vq_p2<<<dim3((BB * NN) / 32), 256, 0, stream>>>(x, ws, cand, out);
}

// Round 11
// 132.902 us; speedup vs baseline: 1.2853x; 1.0044x over previous
//
#include <hip/hip_runtime.h>

#define BB 8
#define NN 4096
#define DD 128
#define KK 1024
#define KSPLIT 4
#define KCOLS 256
#define KSTEP 32
#define NSTEPS (KCOLS / KSTEP)    // 8

typedef _Float16 f16;
typedef f16 f16x8 __attribute__((ext_vector_type(8)));
typedef f16 f16x4 __attribute__((ext_vector_type(4)));
typedef float f32x16 __attribute__((ext_vector_type(16)));

#define MFMA32x16 __builtin_amdgcn_mfma_f32_32x32x16_f16

// ---- ws layout ----
// [0,64KB)       e2d   f64 [8][1024]  (atomic partials; memset 0 each call)
// OFF_HI +2MB    eThi  f16 [8][1024][128]
// OFF_LO +2MB    eTlo  f16 [8][1024][128]
// OFF_TF +4MB    eTf   f32 [8][1024][128]  (exact, gather source)
// OFF_CAND +1MB  cand  float2 [8][4096][KSPLIT]
#define OFF_HI 65536
#define OFF_LO (OFF_HI + 2097152)
#define OFF_TF (OFF_LO + 2097152)
#define OFF_CAND (OFF_TF + 4194304)
#define LOSS_IDX ((size_t)BB * NN * DD)

__device__ __forceinline__ void gload16(const void* g, void* l) {
  __builtin_amdgcn_global_load_lds(
      (const __attribute__((address_space(1))) void*)g,
      (__attribute__((address_space(3))) void*)l, 16, 0, 0);
}

// ====== prep: 512 blocks, float4-coalesced transpose + f16 split + |e|^2 ====
__launch_bounds__(256)
__global__ void vq_prep(const float* __restrict__ emb, char* __restrict__ ws) {
  __shared__ float tile[64][36];        // [k][d], stride 144B (16B-aligned rows)
  const int kt = blockIdx.x;            // 0..15 -> k0 = kt*64
  const int dq = blockIdx.y;            // 0..3  -> d0 = dq*32
  const int b  = blockIdx.z;            // 0..7
  const int t  = threadIdx.x;
  double* e2d = (double*)ws;
  f16*    ehi = (f16*)(ws + OFF_HI);
  f16*    elo = (f16*)(ws + OFF_LO);
  float*  etf = (float*)(ws + OFF_TF);

  const float* eb = emb + ((size_t)b * DD + dq * 32) * KK + kt * 64;
  {                                     // read 32 d-rows x 64 k, float4 along k
    const int k4 = t & 15, dd0 = t >> 4;       // 16 k4-segs x 16 d-rows
#pragma unroll
    for (int p = 0; p < 2; ++p) {
      int d = dd0 + p * 16;
      float4 v = *(const float4*)(eb + (size_t)d * KK + k4 * 4);
      tile[k4 * 4 + 0][d] = v.x;
      tile[k4 * 4 + 1][d] = v.y;
      tile[k4 * 4 + 2][d] = v.z;
      tile[k4 * 4 + 3][d] = v.w;
    }
  }
  __syncthreads();
  {                                     // write along d: 64 k-rows x 8 float4
    const int k0 = t >> 3, seg = t & 7;
#pragma unroll
    for (int p = 0; p < 2; ++p) {
      int k = k0 + p * 32;
      float4 v = *(const float4*)&tile[k][seg * 4];
      size_t base = ((size_t)b * KK + kt * 64 + k) * DD + dq * 32 + seg * 4;
      *(float4*)(etf + base) = v;
      f16 h0 = (f16)v.x, h1 = (f16)v.y, h2 = (f16)v.z, h3 = (f16)v.w;
      *(f16x4*)(ehi + base) = f16x4{h0, h1, h2, h3};
      *(f16x4*)(elo + base) = f16x4{(f16)(v.x - (float)h0), (f16)(v.y - (float)h1),
                                    (f16)(v.z - (float)h2), (f16)(v.w - (float)h3)};
    }
  }
  if (t < 64) {                         // |e|^2 partial over this 32-d chunk
    double acc = 0.0;
#pragma unroll 8
    for (int dd = 0; dd < 32; ++dd) {
      float v = tile[t][dd];
      acc += (double)v * (double)v;
    }
    atomicAdd(e2d + (size_t)b * KK + kt * 64 + t, acc);
  }
}

// ========= p1: f16x3 MFMA distances + per-split argmin (counted vmcnt) =====
__launch_bounds__(256, 2)
__global__ void vq_p1(const float* __restrict__ x, const char* __restrict__ ws,
                      float2* __restrict__ cand) {
  __shared__ __align__(16) char smem[32768];   // 2 x (hi 8KB | lo 8KB)
  const double* e2d = (const double*)ws;
  const f16*    ehi = (const f16*)(ws + OFF_HI);
  const f16*    elo = (const f16*)(ws + OFF_LO);

  const int t = threadIdx.x;
  const int w = t >> 6, lane = t & 63;
  const int r = lane & 31, hb = lane >> 5;
  const int b = blockIdx.y, n0 = blockIdx.x * 128;
  const int sp = blockIdx.z, kb0 = sp * KCOLS;

  // A: 32 rows/wave, f16 hi/lo split in regs (k-slot = hb*8 + j)
  f16x8 ahi[8], alo[8];
  {
    const float* xrow = x + (size_t)(b * NN + n0 + w * 32 + r) * DD;
#pragma unroll
    for (int dc = 0; dc < 8; ++dc) {
      int d0 = dc * 16 + hb * 8;
      float4 f0 = *(const float4*)(xrow + d0);
      float4 f1 = *(const float4*)(xrow + d0 + 4);
      float fv[8] = {f0.x, f0.y, f0.z, f0.w, f1.x, f1.y, f1.z, f1.w};
#pragma unroll
      for (int j = 0; j < 8; ++j) {
        f16 h = (f16)fv[j];
        ahi[dc][j] = h;
        alo[dc][j] = (f16)(fv[j] - (float)h);
      }
    }
  }

  // e2 preload (keeps the K-loop free of stray VMEM ops for counted vmcnt)
  float e2r[NSTEPS];
#pragma unroll
  for (int ks = 0; ks < NSTEPS; ++ks)
    e2r[ks] = (float)e2d[(size_t)b * KK + kb0 + ks * KSTEP + r];

  // stage 32 k-rows (hi+lo = 16KB): 4 gload16 per thread, pre-swizzled source
  auto STAGE = [&](int buf, int ks) {
    const int k0 = kb0 + ks * KSTEP;
    char* hbase = smem + buf * 16384;
    char* lbase = hbase + 8192;
#pragma unroll
    for (int i = 0; i < 2; ++i) {
      int c    = i * 4 + w;                      // 1KB chunk 0..7
      int rloc = c * 4 + (lane >> 4);            // LDS row of this lane's 16B
      int src  = ((lane & 15) << 4) ^ ((rloc & 15) << 4);  // involution
      size_t rowb = (size_t)(b * KK + k0 + rloc) << 8;     // 256B rows
      gload16((const char*)ehi + rowb + src, hbase + c * 1024);
      gload16((const char*)elo + rowb + src, lbase + c * 1024);
    }
  };

  float minv[16]; int mink[16];
#pragma unroll
  for (int j = 0; j < 16; ++j) { minv[j] = 3.4e38f; mink[j] = 0; }

  STAGE(0, 0);

  for (int ks = 0; ks < NSTEPS; ++ks) {
    const int cur = ks & 1;
    // bar1: all waves done reading the buffer we are about to overwrite
    asm volatile("s_waitcnt lgkmcnt(0)" ::: "memory");
    __builtin_amdgcn_s_barrier();
    if (ks < NSTEPS - 1) {
      STAGE(cur ^ 1, ks + 1);                    // 4 loads stay in flight
      asm volatile("s_waitcnt vmcnt(4)" ::: "memory");   // cur's 4 are done
    } else {
      asm volatile("s_waitcnt vmcnt(0)" ::: "memory");
    }
    __builtin_amdgcn_s_barrier();                // bar2: cur staged for all
    const char* hbase = smem + cur * 16384;
    const char* lbase = hbase + 8192;
    f32x16 acc = {};                             // xhi*ehi + xlo*ehi + xhi*elo
    const int swz = (r & 15) << 4;
#pragma unroll
    for (int dc = 0; dc < 8; ++dc) {
      const int off = (dc * 32 + hb * 16) ^ swz; // B k-slot: hb*8 + j
      f16x8 bh = *(const f16x8*)(hbase + r * 256 + off);
      f16x8 bl = *(const f16x8*)(lbase + r * 256 + off);
      acc = MFMA32x16(ahi[dc], bh, acc, 0, 0, 0);
      acc = MFMA32x16(alo[dc], bh, acc, 0, 0, 0);
      acc = MFMA32x16(ahi[dc], bl, acc, 0, 0, 0);
    }
    const int kg = kb0 + ks * KSTEP + r;
    const float e2v = e2r[ks];
#pragma unroll
    for (int j = 0; j < 16; ++j) {
      float s = __builtin_fmaf(-2.f, acc[j], e2v);
      if (s < minv[j]) { minv[j] = s; mink[j] = kg; }   // strict <: first index
    }
  }

  // argmin across the 32 col-lanes (off<32 keeps hb halves separate)
#pragma unroll
  for (int off = 1; off < 32; off <<= 1) {
#pragma unroll
    for (int j = 0; j < 16; ++j) {
      float v2 = __shfl_xor(minv[j], off);
      int   k2 = __shfl_xor(mink[j], off);
      if (v2 < minv[j] || (v2 == minv[j] && k2 < mink[j])) { minv[j] = v2; mink[j] = k2; }
    }
  }
  if (r == 0) {
#pragma unroll
    for (int j = 0; j < 16; ++j) {
      int row = (j & 3) + 8 * (j >> 2) + 4 * hb;   // C/D row map (verified)
      int n = n0 + w * 32 + row;
      cand[(size_t)(b * NN + n) * KSPLIT + sp] =
          make_float2(minv[j], __int_as_float(mink[j]));
    }
  }
}

// ========= p2: merge splits + gather + store + loss ========================
__launch_bounds__(256)
__global__ void vq_p2(const float* __restrict__ x, const char* __restrict__ ws,
                      const float2* __restrict__ cand, float* __restrict__ out) {
  __shared__ int   kidx[32];
  __shared__ float wsum[4];
  const float* etf = (const float*)(ws + OFF_TF);
  const int t = threadIdx.x;
  const int row0 = blockIdx.x * 32;

  if ((t & 7) == 0) {
    int rr = t >> 3;
    const float2* c = cand + (size_t)(row0 + rr) * KSPLIT;
    float bv = c[0].x; int bk = __float_as_int(c[0].y);
#pragma unroll
    for (int s = 1; s < KSPLIT; ++s) {
      float2 p = c[s];
      if (p.x < bv) { bv = p.x; bk = __float_as_int(p.y); }  // k-ascending
    }
    kidx[rr] = bk;
  }
  __syncthreads();

  const int rr = t >> 3, part = t & 7;
  const int grow = row0 + rr;
  const int b = grow >> 12;             // NN = 4096
  const int k = kidx[rr];
  const float4* et = (const float4*)(etf + (size_t)(b * KK + k) * DD + part * 16);
  const float4* xr = (const float4*)(x + (size_t)grow * DD + part * 16);
  float4*       ov = (float4*)(out + (size_t)grow * DD + part * 16);
  float lsum = 0.f;
#pragma unroll
  for (int i = 0; i < 4; ++i) {
    float4 q = et[i], xv = xr[i];
    ov[i] = q;
    float d0 = q.x - xv.x, d1 = q.y - xv.y, d2 = q.z - xv.z, d3 = q.w - xv.w;
    lsum += d0 * d0 + d1 * d1 + d2 * d2 + d3 * d3;
  }
#pragma unroll
  for (int off = 1; off < 64; off <<= 1) lsum += __shfl_xor(lsum, off);
  if ((t & 63) == 0) wsum[t >> 6] = lsum;
  __syncthreads();
  if (t == 0)
    atomicAdd(out + LOSS_IDX, (wsum[0] + wsum[1] + wsum[2] + wsum[3]) *
                                  (1.25f / (float)LOSS_IDX));
}

extern "C" void kernel_launch(void* const* d_in, const int* in_sizes, int n_in,
                              void* d_out, int out_size, void* d_ws, size_t ws_size,
                              hipStream_t stream) {
  const float* x   = (const float*)d_in[0];
  const float* emb = (const float*)d_in[1];
  float* out = (float*)d_out;
  char*  ws  = (char*)d_ws;
  float2* cand = (float2*)(ws + OFF_CAND);

  hipMemsetAsync(ws, 0, 65536, stream);                       // e2d
  hipMemsetAsync(out + LOSS_IDX, 0, sizeof(float), stream);   // loss

  vq_prep<<<dim3(16, 4, BB), 256, 0, stream>>>(emb, ws);
  vq_p1<<<dim3(NN / 128, BB, KSPLIT), 256, 0, stream>>>(x, ws, cand);
  vq_p2<<<dim3((BB * NN) / 32), 256, 0, stream>>>(x, ws, cand, out);
}